// Round 10
// baseline (136.219 us; speedup 1.0000x reference)
//
#include <hip/hip_runtime.h>
#include <math.h>

#define Bsz 120
#define Nv  128
#define Ms  192            // checks per s (rows of Hz for s=0, Hx for s=1)
#define Tit 25
#define EPAD 1280          // 4-aligned edge slots (sum ceil(deg/4)*4 ~ 1068, +8 sigma)
#define KE5 5              // edge slots per thread (EPAD / 256)
#define DC  16             // max check degree (clipped)
#define DV  24             // max var degree

// ws layout (ints): [0] last-block counter | [2..] float part[2][Bsz][Tit]
#define WS_CNT  0
#define WS_PART 2

// phi(x) = -log(tanh(x/2)) = ln2*(log2(1+u) - log2(1-u)), u = e^-x, clip [1e-6,30].
// Small-x: 1-u by series to kill cancellation. (FROZEN: bit-exact vs reference.)
__device__ __forceinline__ float phi_f(float x) {
  x = fminf(fmaxf(x, 1e-6f), 30.0f);
  const float u = __expf(-x);
  float den = 1.0f - u;
  if (x < 0.03125f) den = x * (1.0f - 0.5f * x + 0.16666667f * x * x);
  return 0.69314718f * (__log2f(1.0f + u) - __log2f(den));
}

#define USH(arr, k) ((arr[(k) >> 1] >> (((k) & 1) * 16)) & 0xffff)

// ---------------------------------------------------------------------------
// Fully fused: 240 blocks x 256 threads. Each block (b, s) builds its own
// s-half graph in LDS with a 4-ALIGNED per-check edge layout (window of check
// m starts at rp_al[m] % 4 == 0), runs 25 BP iterations (phase B reads whole
// windows via ds_read_b128), buffers per-iter losses in LDS, writes global
// once, and the last block combines. No vmem in flight at in-loop barriers.
// ---------------------------------------------------------------------------
__global__ __launch_bounds__(256, 1) void nbp_kernel(
    const float* __restrict__ errorx, const float* __restrict__ errorz,
    const float* __restrict__ ep0,
    const float* __restrict__ Hx, const float* __restrict__ Hz,
    const float* __restrict__ Gx, const float* __restrict__ Gz,
    const float* __restrict__ w_llr, const float* __restrict__ w_vn,
    const float* __restrict__ w_cn,
    int* __restrict__ W, float* __restrict__ out) {
  __shared__ unsigned mask_l[Ms][4];        // row bit-masks
  __shared__ int rp_al[Ms + 1];             // 4-aligned window starts
  __shared__ unsigned colmask[Nv][6];       // column bit-masks
  __shared__ unsigned char vcol8[EPAD];     // edge -> var id (Nv = pad sentinel)
  __shared__ unsigned char echk8[EPAD];     // edge -> check id (Ms = pad sentinel)
  __shared__ unsigned short veid_l[Nv * DV];// var -> edge ids (EPAD = pad)
  __shared__ __align__(16) float p_l[EPAD + 16];  // signed phi per edge (+overread pad)
  __shared__ float cn_l[EPAD + 1];          // cn messages; [EPAD] = 0 dummy
  __shared__ float csum_l[Nv + 1];          // per-var cn sum; [Nv] = 0
  __shared__ float2 pt2[256];               // (psum, tot) per padded check
  __shared__ float corrbuf[2][Nv];          // t-parity corr double buffer
  __shared__ float wls[Tit], wvs[Tit], wcs[Tit];
  __shared__ float plost[Tit];              // per-iter loss buffer (LDS, not HBM)
  __shared__ int wtot[3];
  __shared__ float wred[4], wredm[4];
  __shared__ int lastFlag;

  const int tid = threadIdx.x;
  const int lane = tid & 63, wv = tid >> 6;
  const int bid = blockIdx.x;
  const int b = bid >> 1, s = bid & 1;
  float* partBase = (float*)(W + WS_PART);
  float* part = partBase + (s * Bsz + b) * Tit;

  const float ep   = ep0[0];
  const float a23  = (2.0f * ep) / 3.0f;
  const float llr0 = logf((1.0f - a23) / a23);

  // ==== S1: weights; zero colmask; sentinel-init edge arrays; H row masks ====
  if (tid < Tit) {
    wls[tid] = w_llr[tid];
    wvs[tid] = w_vn[tid];
    wcs[tid] = w_cn[tid];
  }
  {
    unsigned* cmf = &colmask[0][0];
    for (int i = tid; i < Nv * 6; i += 256) cmf[i] = 0;
    unsigned* v32 = (unsigned*)veid_l;
    for (int i = tid; i < Nv * DV / 2; i += 256) v32[i] = (EPAD << 16) | EPAD;
#pragma unroll
    for (int k = 0; k < KE5; ++k) {
      const int e = tid + (k << 8);
      vcol8[e] = (unsigned char)Nv;
      echk8[e] = (unsigned char)Ms;
    }
  }
  unsigned mwa[4] = {0, 0, 0, 0};
  int d = 0;
  if (tid < Ms) {
    const float4* H4 = (const float4*)((s ? Hx : Hz) + tid * Nv);  // Hs=[Hz,Hx]
#pragma unroll
    for (int w = 0; w < 4; ++w) {
      unsigned bits = 0;
#pragma unroll
      for (int q = 0; q < 8; ++q) {
        const float4 v = H4[w * 8 + q];
        if (v.x > 0.f) bits |= 1u << (q * 4 + 0);
        if (v.y > 0.f) bits |= 1u << (q * 4 + 1);
        if (v.z > 0.f) bits |= 1u << (q * 4 + 2);
        if (v.w > 0.f) bits |= 1u << (q * 4 + 3);
      }
      mwa[w] = bits;
      mask_l[tid][w] = bits;
      d += __popc(bits);
    }
  }
  const int dgc = (d <= DC) ? d : DC;       // clipped degree
  const int d4  = (dgc + 3) & ~3;           // aligned window size
  __syncthreads();

  // ==== S2: shfl prefix scan of window sizes -> rp_al ====
  {
    int x = d4;
#pragma unroll
    for (int off = 1; off < 64; off <<= 1) {
      const int y = __shfl_up(x, off);
      if (lane >= off) x += y;
    }
    if (lane == 63 && wv < 3) wtot[wv] = x;
    __syncthreads();
    int carry = 0;
    for (int k = 0; k < wv && k < 3; ++k) carry += wtot[k];
    if (tid < Ms) {
      const int incl = x + carry;
      rp_al[tid] = incl - d4;
      if (tid == Ms - 1) rp_al[Ms] = incl;
    }
  }
  __syncthreads();

  // ==== S3: emit edges into aligned windows + column-mask transpose ====
  if (tid < Ms) {
    int o = rp_al[tid];
    const unsigned wbit = 1u << (tid & 31);
    const int wrd = tid >> 5;
    int cnt = 0;
#pragma unroll
    for (int w = 0; w < 4; ++w) {
      unsigned bits = mwa[w];
      while (bits) {
        const int j = __ffs(bits) - 1;
        bits &= bits - 1;
        const int n = w * 32 + j;
        if (cnt < DC && o < EPAD) {
          vcol8[o] = (unsigned char)n;
          echk8[o] = (unsigned char)tid;
          ++o;
        }
        ++cnt;
        atomicOr(&colmask[n][wrd], wbit);
      }
    }
  }
  if (tid < Nv) {
    const float* esyn = (s ? errorz : errorx) + b * Nv;  // syndrome selector
    csum_l[tid] = esyn[tid];              // temp stage
  }
  if (tid == 0) {
    csum_l[Nv] = 0.f;
    cn_l[EPAD] = 0.f;
  }
  __syncthreads();

  // ==== S4: reg tables; veid build; stage edge signs for syndrome ====
  unsigned vcolp[3] = {0, 0, 0}, chkp[3] = {0, 0, 0};
#pragma unroll
  for (int k = 0; k < KE5; ++k) {
    const int e = tid + (k << 8);
    vcolp[k >> 1] |= ((unsigned)vcol8[e]) << ((k & 1) * 16);
    chkp[k >> 1]  |= ((unsigned)echk8[e]) << ((k & 1) * 16);
  }
  const int rp0 = (tid < Ms) ? rp_al[tid] : 0;
  const int dg0 = (tid < Ms) ? dgc : 0;
  if (tid < Nv) {
    const int wnd = tid >> 5;
    const unsigned lowmask = (1u << (tid & 31)) - 1u;
    int kk = 0;
#pragma unroll
    for (int w6 = 0; w6 < 6; ++w6) {
      unsigned bits = colmask[tid][w6];
      while (bits) {
        const int m2 = w6 * 32 + (__ffs(bits) - 1);
        bits &= bits - 1;
        int r = __popc(mask_l[m2][wnd] & lowmask);
        for (int w = 0; w < wnd; ++w) r += __popc(mask_l[m2][w]);
        if (kk < DV && r < DC) veid_l[tid * DV + kk] = (unsigned short)(rp_al[m2] + r);
        if (r < DC) ++kk;
      }
    }
  }
#pragma unroll
  for (int k = 0; k < KE5; ++k) {         // stage signs (pads get +1, unread)
    const int e = tid + (k << 8);
    const int nn = USH(vcolp, k);
    p_l[e] = (csum_l[nn] > 0.5f) ? -1.f : 1.f;
  }
  const int l2 = tid - 128;
  float g0a = 0.f, g0b = 0.f, g1a = 0.f, g1b = 0.f;
  if (tid >= 128 && tid < 192) {
    const float* G = s ? Gz : Gx;         // s=0: Gx·corrz ; s=1: Gz·corrx
    g0a = G[l2]; g0b = G[l2 + 64];
    g1a = G[Nv + l2]; g1b = G[Nv + l2 + 64];
  }
  float ec = 0.f;
  if (tid < Nv) ec = ((s ? errorx : errorz) + b * Nv)[tid];
  __syncthreads();

  // ==== S5: vep regs + syndrome parity (window b128 reads, predicated) ====
  unsigned vep[12];
  if (tid < Nv) {
    const uint4* q = (const uint4*)(veid_l + tid * DV);
    const uint4 a0 = q[0], a1 = q[1], a2 = q[2];
    vep[0] = a0.x; vep[1] = a0.y; vep[2]  = a0.z; vep[3]  = a0.w;
    vep[4] = a1.x; vep[5] = a1.y; vep[6]  = a1.z; vep[7]  = a1.w;
    vep[8] = a2.x; vep[9] = a2.y; vep[10] = a2.z; vep[11] = a2.w;
  } else {
#pragma unroll
    for (int i = 0; i < 12; ++i) vep[i] = (EPAD << 16) | EPAD;
  }
  float ssgn;
  {
    const float4* pp = (const float4*)(p_l + rp0);
    const float4 f0 = pp[0], f1 = pp[1], f2 = pp[2], f3 = pp[3];
    const float vals[16] = {f0.x, f0.y, f0.z, f0.w, f1.x, f1.y, f1.z, f1.w,
                            f2.x, f2.y, f2.z, f2.w, f3.x, f3.y, f3.z, f3.w};
    unsigned par = 0;
#pragma unroll
    for (int k = 0; k < DC; ++k)
      if (k < dg0) par ^= __float_as_uint(vals[k]) >> 31;
    ssgn = (par & 1u) ? -1.f : 1.f;
  }
  __syncthreads();

  // ==== main 25-iteration BP loop ====
  float cn_reg[KE5] = {0.f, 0.f, 0.f, 0.f, 0.f};
  float basePrev = llr0, wvPrev = 0.f;    // t=0 reconstructs V = llr0 exactly

#pragma unroll 1
  for (int t = 0; t < Tit; ++t) {
    const float wct = wcs[t];

    // ---- A: 5 edges/thread, phi; keep p in regs, store for B ----
    float pe[KE5];
#pragma unroll
    for (int k = 0; k < KE5; ++k) {
      const int e = tid + (k << 8);
      const int nn = USH(vcolp, k);
      const float csv = csum_l[nn];
      const float Vk = basePrev + wvPrev * (csv - cn_reg[k]);
      float pv = phi_f(fabsf(Vk));
      pv = fmaxf(pv, 1e-30f);
      pv = (Vk < 0.f) ? -pv : pv;
      pe[k] = pv;
      p_l[e] = pv;
    }
    __syncthreads();

    // ---- B: 1 check/thread; window fetch via 4x ds_read_b128, predicated
    //         accumulation in k-ascending order (bit-exact vs scalar) ----
    {
      const float4* pp = (const float4*)(p_l + rp0);
      const float4 f0 = pp[0], f1 = pp[1], f2 = pp[2], f3 = pp[3];
      const float vals[16] = {f0.x, f0.y, f0.z, f0.w, f1.x, f1.y, f1.z, f1.w,
                              f2.x, f2.y, f2.z, f2.w, f3.x, f3.y, f3.z, f3.w};
      float psum = 0.f;
      unsigned par = 0;
#pragma unroll
      for (int k = 0; k < DC; ++k)
        if (k < dg0) {
          par ^= __float_as_uint(vals[k]) >> 31;
          psum += fabsf(vals[k]);
        }
      const float tt = ((par & 1u) ? -ssgn : ssgn) * wct;
      pt2[tid] = make_float2(psum, tt);
    }
    __syncthreads();

    // ---- C: 5 edges/thread cn; reuse reg p; store for D ----
#pragma unroll
    for (int k = 0; k < KE5; ++k) {
      const int cc = USH(chkp, k);
      const float2 q = pt2[cc];
      const float ps = pe[k];
      const float sg = (__float_as_uint(ps) >> 31) ? -1.f : 1.f;
      const float cnk = q.y * sg * phi_f(q.x - fabsf(ps));
      cn_reg[k] = cnk;
      cn_l[tid + (k << 8)] = cnk;
    }
    __syncthreads();

    // ---- D: var gather + corr (tid<128) || loss(t-1) -> plost (wave 2) ----
    const float base_t = wls[t] * llr0;
    if (tid < Nv) {
      float cs = 0.f;
#pragma unroll
      for (int k = 0; k < DV; ++k) cs += cn_l[USH(vep, k)];
      csum_l[tid] = cs;
      const float prob = 1.0f / (1.0f + __expf(base_t + cs));  // sigmoid(-Gamma)
      corrbuf[t & 1][tid] = (ec > 0.5f) ? 1.0f - prob : prob;
    } else if (tid < 192 && t > 0) {
      const float* cr = corrbuf[(t - 1) & 1];
      const float c0 = cr[l2], c1 = cr[l2 + 64];
      float la = g0a * c0 + g0b * c1;
      float lb = g1a * c0 + g1b * c1;
#pragma unroll
      for (int off = 1; off < 64; off <<= 1) {
        la += __shfl_xor(la, off);
        lb += __shfl_xor(lb, off);
      }
      const float lt = fabsf(__sinf(1.57079632679f * la)) +
                       fabsf(__sinf(1.57079632679f * lb));
      if (l2 == 0) plost[t - 1] = lt;
    }
    basePrev = base_t;
    wvPrev = wvs[t];
    __syncthreads();
  }

  // ---- loss of final iteration (wave 2) ----
  if (tid >= 128 && tid < 192) {
    const float* cr = corrbuf[(Tit - 1) & 1];
    const float c0 = cr[l2], c1 = cr[l2 + 64];
    float la = g0a * c0 + g0b * c1;
    float lb = g1a * c0 + g1b * c1;
#pragma unroll
    for (int off = 1; off < 64; off <<= 1) {
      la += __shfl_xor(la, off);
      lb += __shfl_xor(lb, off);
    }
    const float lt = fabsf(__sinf(1.57079632679f * la)) +
                     fabsf(__sinf(1.57079632679f * lb));
    if (l2 == 0) plost[Tit - 1] = lt;
  }
  __syncthreads();

  // ---- single global write of this chain's 25 losses ----
  if (tid < Tit) part[tid] = plost[tid];

  // ---- fused final combine: threadfence + atomic counter, last block ----
  __threadfence();
  if (tid == 0) lastFlag = (atomicAdd(W + WS_CNT, 1) == 2 * Bsz - 1);
  __syncthreads();
  if (lastFlag) {
    __threadfence();
    float sm = 0.f, mn = 0.f;
    if (tid < Bsz) {
      const float* pa = partBase + tid * Tit;            // s=0
      const float* pb = partBase + (Bsz + tid) * Tit;    // s=1
      float acc = 0.f, mloc = 3.0e38f;
#pragma unroll
      for (int t = 0; t < Tit; ++t) {
        const float lt = pa[t] + pb[t];
        acc += lt;
        mloc = fminf(mloc, lt);
      }
      sm = acc;
      mn = mloc;
    }
#pragma unroll
    for (int off = 32; off; off >>= 1) {
      sm += __shfl_down(sm, off);
      mn += __shfl_down(mn, off);
    }
    if ((tid & 63) == 0) { wred[tid >> 6] = sm; wredm[tid >> 6] = mn; }
    __syncthreads();
    if (tid == 0) {
      out[0] = (wred[0] + wred[1]) * (1.0f / Bsz);
      out[1] = (wredm[0] + wredm[1]) * (1.0f / Bsz);
    }
  }
}

extern "C" void kernel_launch(void* const* d_in, const int* in_sizes, int n_in,
                              void* d_out, int out_size, void* d_ws, size_t ws_size,
                              hipStream_t stream) {
  const float* errorx = (const float*)d_in[0];
  const float* errorz = (const float*)d_in[1];
  const float* ep0    = (const float*)d_in[2];
  const float* Hx     = (const float*)d_in[3];
  const float* Hz     = (const float*)d_in[4];
  const float* Gx     = (const float*)d_in[5];
  const float* Gz     = (const float*)d_in[6];
  const float* wllr   = (const float*)d_in[7];
  const float* wvn    = (const float*)d_in[8];
  const float* wcn    = (const float*)d_in[9];
  float* out = (float*)d_out;
  int* W = (int*)d_ws;

  hipMemsetAsync((void*)(W + WS_CNT), 0, sizeof(int), stream);  // zero counter
  hipLaunchKernelGGL(nbp_kernel, dim3(2 * Bsz), dim3(256), 0, stream,
                     errorx, errorz, ep0, Hx, Hz, Gx, Gz, wllr, wvn, wcn, W, out);
}